// Round 8
// baseline (233.453 us; speedup 1.0000x reference)
//
#include <hip/hip_runtime.h>
#include <cstdint>
#include <cstddef>

// ---------------- types ----------------
typedef __attribute__((ext_vector_type(4)))  float  floatx4;
typedef __attribute__((ext_vector_type(16))) float  f32x16;
typedef __attribute__((ext_vector_type(8)))  __bf16 bf16x8;
typedef __attribute__((ext_vector_type(8)))  unsigned short u16x8;

#define M_TOT 16384   // B*S
#define N_TOT 2048    // D_OUT
#define K_TOT 2048    // D_IN
#define NBATCH 8
#define RLORA 16
#define NT 32         // K tiles of 64

// f32 -> bf16 round-to-nearest-even
__device__ __forceinline__ unsigned short f32_to_bf16(float f) {
  unsigned u = __float_as_uint(f);
  u += 0x7fffu + ((u >> 16) & 1u);
  return (unsigned short)(u >> 16);
}

__device__ __forceinline__ u16x8 cvt8(const float4& a, const float4& b) {
  u16x8 o;
  o[0] = f32_to_bf16(a.x); o[1] = f32_to_bf16(a.y);
  o[2] = f32_to_bf16(a.z); o[3] = f32_to_bf16(a.w);
  o[4] = f32_to_bf16(b.x); o[5] = f32_to_bf16(b.y);
  o[6] = f32_to_bf16(b.z); o[7] = f32_to_bf16(b.w);
  return o;
}

// async global->LDS, 16B per lane (LDS dest wave-uniform base + lane*16)
#define GLOAD_LDS16(gp, lp)                                                        \
  __builtin_amdgcn_global_load_lds((__attribute__((address_space(1))) void*)(void*)(gp), \
                                   (__attribute__((address_space(3))) void*)(void*)(lp), \
                                   16, 0, 0)

template<int V> struct IC { static constexpr int value = V; };

// ---------------- merged prep: W convert | Ap pack | fused x-convert + inter ----------------
// grid 3136 x 256thr: b<2048 -> W; b<2112 -> Ap ([8*2048][16] bf16, unpadded);
// b>=2112 -> xinter block (16 rows, 4 waves split K): xbf=bf16(x), inter=x@Bp^T.
__global__ __launch_bounds__(256) void k_prep(const float* __restrict__ W, const float* __restrict__ Ap,
                                              const float* __restrict__ x, const float* __restrict__ Bp,
                                              unsigned short* __restrict__ wbf, unsigned short* __restrict__ abf,
                                              unsigned short* __restrict__ xbf, unsigned short* __restrict__ interbf) {
  __shared__ floatx4 red[4][64];
  const int b = blockIdx.x;
  const int tid = threadIdx.x;
  if (b < 2048) {                       // W: 4.19M elems = 524288 8-elem units
    int i = b * 256 + tid;
    const float4* p = (const float4*)W + (size_t)i * 2;
    *(u16x8*)(wbf + (size_t)i * 8) = cvt8(p[0], p[1]);
    return;
  }
  if (b < 2112) {                       // Ap: [16384][16] f32 -> bf16
    int row = (b - 2048) * 256 + tid;
    const float4* p = (const float4*)(Ap + (size_t)row * RLORA);
    u16x8* dst = (u16x8*)(abf + (size_t)row * RLORA);
    dst[0] = cvt8(p[0], p[1]);
    dst[1] = cvt8(p[2], p[3]);
    return;
  }
  // ---- xinter: block m-tile (16 rows), 4 waves split K (512 each) ----
  const int lane = tid & 63;
  const int wv   = tid >> 6;
  const int l15  = lane & 15;
  const int hi   = lane >> 4;
  const int m0   = (b - 2112) * 16;
  const int bb   = m0 >> 11;

  floatx4 acc = {0.f, 0.f, 0.f, 0.f};
  const float* bpb = Bp + (size_t)bb * (RLORA * K_TOT);
  const size_t xrow = (size_t)(m0 + l15) * K_TOT;
  const size_t brow = (size_t)l15 * K_TOT;
  const int kb0 = wv * 512;
  for (int kb = kb0; kb < kb0 + 512; kb += 32) {
    const float* xp = x + xrow + kb + hi * 8;
    u16x8 ao = cvt8(*(const float4*)xp, *(const float4*)(xp + 4));
    *(u16x8*)(xbf + xrow + kb + hi * 8) = ao;
    const float* bpp = bpb + brow + kb + hi * 8;
    u16x8 bo = cvt8(*(const float4*)bpp, *(const float4*)(bpp + 4));
    acc = __builtin_amdgcn_mfma_f32_16x16x32_bf16(*(bf16x8*)&ao, *(bf16x8*)&bo, acc, 0, 0, 0);
  }
  red[wv][lane] = acc;
  __syncthreads();
  if (wv == 0) {
    floatx4 s = red[0][lane] + red[1][lane] + red[2][lane] + red[3][lane];
    #pragma unroll
    for (int j = 0; j < 4; ++j) {
      int m = m0 + hi * 4 + j;          // 16x16 C/D: row = hi*4+j, col = l15 = r
      interbf[(size_t)m * RLORA + l15] = f32_to_bf16(s[j]);
    }
  }
}

// ---------------- main GEMM: 256x256, BK=64, 8 waves, 8-phase — 32x32x16 MFMA ----------------
// Same sync skeleton as R6/R7 (phases, stages, counted vmcnt). Fragment shapes changed:
// per wave 128x64 = 4 m-tiles x 2 n-tiles of 32x32; K=64 = 4 k-steps of 16.
// A/B operand layout (32x32x16): lane l -> row=l&31, k=(l>>5)*8+j (4 VGPRs, 8 bf16).
// C/D layout: col=l&31, row=(reg&3)+8*(reg>>2)+4*(l>>5)  [m74/m101].
// LoRA: rank 16 == K -> exact mfma_32x32x16, no padding.
#define STAGE_A(bufi, h, tt) do {                                                      \
  GLOAD_LDS16(Ag + (h)*262144 + (tt)*64 + gOff0, AsB + ((bufi)*2+(h))*16384 + ldsB0);  \
  GLOAD_LDS16(Ag + (h)*262144 + (tt)*64 + gOff1, AsB + ((bufi)*2+(h))*16384 + ldsB1);  \
} while(0)
#define STAGE_B(bufi, h, tt) do {                                                      \
  GLOAD_LDS16(Bg + (h)*262144 + (tt)*64 + gOff0, BsB + ((bufi)*2+(h))*16384 + ldsB0);  \
  GLOAD_LDS16(Bg + (h)*262144 + (tt)*64 + gOff1, BsB + ((bufi)*2+(h))*16384 + ldsB1);  \
} while(0)
#define RDA_(B2, mt, ks) (*(const bf16x8*)(AsB + (B2)*32768 + aBase + (mt)*4096 + koff[ks]))
#define RDB_(B2, nt, ks) (*(const bf16x8*)(BsB + (B2)*32768 + bBase + (nt)*4096 + koff[ks]))
#define BAR() __builtin_amdgcn_s_barrier()

__global__ __launch_bounds__(512, 2) void k_gemm(const unsigned short* __restrict__ xbf,
                                                 const unsigned short* __restrict__ wbf,
                                                 const unsigned short* __restrict__ interbf,
                                                 const unsigned short* __restrict__ abf,
                                                 const float* __restrict__ bias,
                                                 float* __restrict__ out) {
  __shared__ unsigned short As[2][2][8192];
  __shared__ unsigned short Bs[2][2][8192];
  const int tid  = threadIdx.x;
  const int lane = tid & 63;
  const int wid  = tid >> 6;     // 0..7
  const int wm   = wid >> 2;     // 0..1
  const int wn   = wid & 3;      // 0..3
  const int l31  = lane & 31;
  const int g    = lane >> 5;    // 0..1 (k-group)

  // XCD-aware bijective swizzle: grid 512 = 64 mt x 8 nt
  int bid  = blockIdx.x;
  int swzb = ((bid & 7) << 6) | (bid >> 3);
  const int mt_ = swzb >> 3;
  const int nt_ = swzb & 7;
  const int mrow0 = mt_ << 8;
  const int ncol0 = nt_ << 8;
  const int bb = mrow0 >> 11;

  const int m0 = mrow0 + wm * 128;
  const int n0 = ncol0 + wn * 64;

  const unsigned short* Ag = xbf + (size_t)mrow0 * K_TOT;
  const unsigned short* Bg = wbf + (size_t)ncol0 * K_TOT;
  char* AsB = (char*)As;
  char* BsB = (char*)Bs;

  // staging offsets (pre-swizzled source; linear LDS dest) — unchanged
  const int r0    = tid >> 3;
  const int k80   = (tid & 7) ^ (r0 & 7);
  const int gOff0 = r0 * K_TOT + k80 * 8;
  const int gOff1 = gOff0 + 64 * K_TOT;
  const int ldsB0 = wid * 1024;
  const int ldsB1 = 8192 + wid * 1024;

  // fragment read bases (byte offsets). Per-read: lane -> row l31 of tile, chunk (ks*2+g)^(row&7).
  const int aBase = wm * 16384 + l31 * 128;
  const int bBase = (wn >> 1) * 16384 + (wn & 1) * 8192 + l31 * 128;
  int koff[4];
  #pragma unroll
  for (int ks = 0; ks < 4; ++ks) koff[ks] = ((ks * 2 + g) ^ (l31 & 7)) * 16;

  f32x16 acc[4][2];
  bf16x8 bfr[2][4];   // B-frags [nt][ks]: held for a whole K-tile
  bf16x8 af[4];       // A-frags for one m-tile (4 k-steps): fresh each phase

  // ---- prologue: LoRA acc-init (exact K=16) + stage 6 half-tiles ----
  {
    bf16x8 la[4], lb[2];
    #pragma unroll
    for (int mt = 0; mt < 4; ++mt)
      la[mt] = *(const bf16x8*)(interbf + (size_t)(m0 + mt * 32 + l31) * RLORA + g * 8);
    #pragma unroll
    for (int nt = 0; nt < 2; ++nt)
      lb[nt] = *(const bf16x8*)(abf + ((size_t)bb * N_TOT + n0 + nt * 32 + l31) * RLORA + g * 8);

    STAGE_A(0, 0, 0); STAGE_A(0, 1, 0); STAGE_B(0, 0, 0); STAGE_B(0, 1, 0);
    STAGE_B(1, 0, 1); STAGE_B(1, 1, 1);

    f32x16 z = {0.f};
    #pragma unroll
    for (int mt = 0; mt < 4; ++mt)
      #pragma unroll
      for (int nt = 0; nt < 2; ++nt)
        acc[mt][nt] = __builtin_amdgcn_mfma_f32_32x32x16_bf16(la[mt], lb[nt], z, 0, 0, 0);
  }
  asm volatile("s_waitcnt vmcnt(4)" ::: "memory");   // t0's 4 halves landed; t1's B pair in flight
  BAR();

  auto tile_step = [&](int t, auto bufc, auto sac, auto sbc, auto vmc) {
    constexpr int BUF = decltype(bufc)::value;
    constexpr int SA  = decltype(sac)::value;   // stage A0,A1(t+1) -> BUF^1 at ph1,ph2
    constexpr int SB  = decltype(sbc)::value;   // stage B0,B1(t+2) -> BUF at ph3,ph4
    constexpr int VM  = decltype(vmc)::value;   // ph4-end vmcnt: 4, 0, or -1

    // ---- ph1: read B-all(8) + A m-tile0(4); stage A0(t+1); MFMA mt=0
    #pragma unroll
    for (int nt = 0; nt < 2; ++nt)
      #pragma unroll
      for (int ks = 0; ks < 4; ++ks) bfr[nt][ks] = RDB_(BUF, nt, ks);
    #pragma unroll
    for (int ks = 0; ks < 4; ++ks) af[ks] = RDA_(BUF, 0, ks);
    if constexpr (SA) STAGE_A(BUF ^ 1, 0, t + 1);
    BAR();
    __builtin_amdgcn_s_setprio(1);
    #pragma unroll
    for (int ks = 0; ks < 4; ++ks)
      #pragma unroll
      for (int nt = 0; nt < 2; ++nt)
        acc[0][nt] = __builtin_amdgcn_mfma_f32_32x32x16_bf16(af[ks], bfr[nt][ks], acc[0][nt], 0, 0, 0);
    __builtin_amdgcn_s_setprio(0);
    BAR();

    // ---- ph2: read A m-tile1; stage A1(t+1); MFMA mt=1
    #pragma unroll
    for (int ks = 0; ks < 4; ++ks) af[ks] = RDA_(BUF, 1, ks);
    if constexpr (SA) STAGE_A(BUF ^ 1, 1, t + 1);
    BAR();
    __builtin_amdgcn_s_setprio(1);
    #pragma unroll
    for (int ks = 0; ks < 4; ++ks)
      #pragma unroll
      for (int nt = 0; nt < 2; ++nt)
        acc[1][nt] = __builtin_amdgcn_mfma_f32_32x32x16_bf16(af[ks], bfr[nt][ks], acc[1][nt], 0, 0, 0);
    __builtin_amdgcn_s_setprio(0);
    BAR();

    // ---- ph3: read A m-tile2; stage B0(t+2); MFMA mt=2
    #pragma unroll
    for (int ks = 0; ks < 4; ++ks) af[ks] = RDA_(BUF, 2, ks);
    if constexpr (SB) STAGE_B(BUF, 0, t + 2);
    BAR();
    __builtin_amdgcn_s_setprio(1);
    #pragma unroll
    for (int ks = 0; ks < 4; ++ks)
      #pragma unroll
      for (int nt = 0; nt < 2; ++nt)
        acc[2][nt] = __builtin_amdgcn_mfma_f32_32x32x16_bf16(af[ks], bfr[nt][ks], acc[2][nt], 0, 0, 0);
    __builtin_amdgcn_s_setprio(0);
    BAR();

    // ---- ph4: read A m-tile3; stage B1(t+2); MFMA mt=3; vmcnt at end
    #pragma unroll
    for (int ks = 0; ks < 4; ++ks) af[ks] = RDA_(BUF, 3, ks);
    if constexpr (SB) STAGE_B(BUF, 1, t + 2);
    BAR();
    __builtin_amdgcn_s_setprio(1);
    #pragma unroll
    for (int ks = 0; ks < 4; ++ks)
      #pragma unroll
      for (int nt = 0; nt < 2; ++nt)
        acc[3][nt] = __builtin_amdgcn_mfma_f32_32x32x16_bf16(af[ks], bfr[nt][ks], acc[3][nt], 0, 0, 0);
    __builtin_amdgcn_s_setprio(0);
    if constexpr (VM == 4)      asm volatile("s_waitcnt vmcnt(4)" ::: "memory");
    else if constexpr (VM == 0) asm volatile("s_waitcnt vmcnt(0)" ::: "memory");
    BAR();
  };

  for (int t = 0; t < NT - 2; t += 2) {
    tile_step(t,     IC<0>{}, IC<1>{}, IC<1>{}, IC<4>{});
    tile_step(t + 1, IC<1>{}, IC<1>{}, IC<1>{}, IC<4>{});
  }
  tile_step(NT - 2, IC<0>{}, IC<1>{}, IC<0>{}, IC<0>{});
  tile_step(NT - 1, IC<1>{}, IC<0>{}, IC<0>{}, IC<-1>{});

  // ---- epilogue: + bias, store f32. 32x32 C/D: col=l31, row=(reg&3)+8*(reg>>2)+4*g ----
  #pragma unroll
  for (int nt = 0; nt < 2; ++nt) {
    int col = n0 + nt * 32 + l31;
    float bv = bias[col];
    #pragma unroll
    for (int mt = 0; mt < 4; ++mt) {
      #pragma unroll
      for (int reg = 0; reg < 16; ++reg) {
        int row = m0 + mt * 32 + (reg & 3) + 8 * (reg >> 2) + 4 * g;
        out[(size_t)row * N_TOT + col] = acc[mt][nt][reg] + bv;
      }
    }
  }
}

// ---------------- launcher ----------------
extern "C" void kernel_launch(void* const* d_in, const int* in_sizes, int n_in,
                              void* d_out, int out_size, void* d_ws, size_t ws_size,
                              hipStream_t stream) {
  const float* x    = (const float*)d_in[0];   // [8,2048,2048]
  const float* Ap   = (const float*)d_in[1];   // [8,2048,16]
  const float* Bp   = (const float*)d_in[2];   // [8,16,2048]
  const float* W    = (const float*)d_in[3];   // [2048,2048]
  const float* bias = (const float*)d_in[4];   // [2048]
  float* out = (float*)d_out;

  char* ws = (char*)d_ws;
  unsigned short* xbf     = (unsigned short*)(ws);                        // 64 MiB
  unsigned short* wbf     = (unsigned short*)(ws + 67108864);             // 8 MiB
  unsigned short* abf     = (unsigned short*)(ws + 75497472);             // 0.5 MiB [16384][16]
  unsigned short* interbf = (unsigned short*)(ws + 76021760);             // 0.5 MiB [16384][16]

  k_prep<<<dim3(3136), dim3(256), 0, stream>>>(W, Ap, x, Bp, wbf, abf, xbf, interbf);
  k_gemm<<<dim3(512), dim3(512), 0, stream>>>(xbf, wbf, interbf, abf, bias, out);
}

// Round 9
// 192.907 us; speedup vs baseline: 1.2102x; 1.2102x over previous
//
#include <hip/hip_runtime.h>
#include <cstdint>
#include <cstddef>

// ---------------- types ----------------
typedef __attribute__((ext_vector_type(4))) float  floatx4;
typedef __attribute__((ext_vector_type(8))) __bf16 bf16x8;
typedef __attribute__((ext_vector_type(8))) unsigned short u16x8;

#define M_TOT 16384   // B*S
#define N_TOT 2048    // D_OUT
#define K_TOT 2048    // D_IN
#define NBATCH 8
#define RLORA 16
#define NT 32         // K tiles of 64

// f32 -> bf16 round-to-nearest-even
__device__ __forceinline__ unsigned short f32_to_bf16(float f) {
  unsigned u = __float_as_uint(f);
  u += 0x7fffu + ((u >> 16) & 1u);
  return (unsigned short)(u >> 16);
}

__device__ __forceinline__ u16x8 cvt8(const float4& a, const float4& b) {
  u16x8 o;
  o[0] = f32_to_bf16(a.x); o[1] = f32_to_bf16(a.y);
  o[2] = f32_to_bf16(a.z); o[3] = f32_to_bf16(a.w);
  o[4] = f32_to_bf16(b.x); o[5] = f32_to_bf16(b.y);
  o[6] = f32_to_bf16(b.z); o[7] = f32_to_bf16(b.w);
  return o;
}

// async global->LDS, 16B per lane (LDS dest wave-uniform base + lane*16)
#define GLOAD_LDS16(gp, lp)                                                        \
  __builtin_amdgcn_global_load_lds((__attribute__((address_space(1))) void*)(void*)(gp), \
                                   (__attribute__((address_space(3))) void*)(void*)(lp), \
                                   16, 0, 0)

template<int V> struct IC { static constexpr int value = V; };

// ---------------- combined small converts: W (2048 blocks) | A_params pack (64 blocks) ----------------
__global__ void k_convert_small(const float* __restrict__ W, const float* __restrict__ Ap,
                                unsigned short* __restrict__ wbf, unsigned short* __restrict__ abf) {
  int b = blockIdx.x;
  if (b < 2048) {
    int i = b * 256 + threadIdx.x;
    const float4* p = (const float4*)W + (size_t)i * 2;
    *(u16x8*)(wbf + (size_t)i * 8) = cvt8(p[0], p[1]);
  } else {
    int row = (b - 2048) * 256 + threadIdx.x;
    const float4* p = (const float4*)(Ap + (size_t)row * RLORA);
    u16x8 lo = cvt8(p[0], p[1]), hi2 = cvt8(p[2], p[3]), z = {0,0,0,0,0,0,0,0};
    u16x8* dst = (u16x8*)(abf + (size_t)row * 32);
    dst[0] = lo; dst[1] = hi2; dst[2] = z; dst[3] = z;
  }
}

// ---------------- fused: xbf = bf16(x) AND inter = x @ Bp^T ----------------
// 1024 blocks x 512 thr; block = 16 rows (one m-tile); 8 waves split K (256 each).
// The f32 x load IS the MFMA A-fragment (row=l15, k=hi*8+j). Bp (2 MiB f32) is L2-resident.
__global__ __launch_bounds__(512) void k_xinter(const float* __restrict__ x,
                                                const float* __restrict__ Bp,
                                                unsigned short* __restrict__ xbf,
                                                unsigned short* __restrict__ interbf) {
  const int tid  = threadIdx.x;
  const int lane = tid & 63;
  const int wv   = tid >> 6;          // 0..7
  const int l15  = lane & 15;
  const int hi   = lane >> 4;
  const int m0   = blockIdx.x * 16;
  const int bb   = m0 >> 11;

  floatx4 acc = {0.f, 0.f, 0.f, 0.f};
  const float* bpb = Bp + (size_t)bb * (RLORA * K_TOT);
  const size_t xrow = (size_t)(m0 + l15) * K_TOT;
  const size_t brow = (size_t)l15 * K_TOT;
  const int kb0 = wv * 256;
  for (int kb = kb0; kb < kb0 + 256; kb += 32) {
    const float* xp = x + xrow + kb + hi * 8;
    u16x8 ao = cvt8(*(const float4*)xp, *(const float4*)(xp + 4));
    *(u16x8*)(xbf + xrow + kb + hi * 8) = ao;
    const float* bpp = bpb + brow + kb + hi * 8;
    u16x8 bo = cvt8(*(const float4*)bpp, *(const float4*)(bpp + 4));
    acc = __builtin_amdgcn_mfma_f32_16x16x32_bf16(*(bf16x8*)&ao, *(bf16x8*)&bo, acc, 0, 0, 0);
  }

  __shared__ floatx4 red[8][64];
  red[wv][lane] = acc;
  __syncthreads();
  if (wv == 0) {
    floatx4 s = red[0][lane] + red[1][lane] + red[2][lane] + red[3][lane]
              + red[4][lane] + red[5][lane] + red[6][lane] + red[7][lane];
    #pragma unroll
    for (int j = 0; j < 4; ++j) {
      int m = m0 + hi * 4 + j;          // C/D layout: row = hi*4+j, col = l15 = r
      interbf[(size_t)m * 32 + l15] = f32_to_bf16(s[j]);
      interbf[(size_t)m * 32 + 16 + l15] = 0;
    }
  }
}

// ---------------- main GEMM: 256x256, BK=64, 8 waves, 8-phase (R7 exact) ----------------
#define STAGE_A(bufi, h, tt) do {                                                      \
  GLOAD_LDS16(Ag + (h)*262144 + (tt)*64 + gOff0, AsB + ((bufi)*2+(h))*16384 + ldsB0);  \
  GLOAD_LDS16(Ag + (h)*262144 + (tt)*64 + gOff1, AsB + ((bufi)*2+(h))*16384 + ldsB1);  \
} while(0)
#define STAGE_B(bufi, h, tt) do {                                                      \
  GLOAD_LDS16(Bg + (h)*262144 + (tt)*64 + gOff0, BsB + ((bufi)*2+(h))*16384 + ldsB0);  \
  GLOAD_LDS16(Bg + (h)*262144 + (tt)*64 + gOff1, BsB + ((bufi)*2+(h))*16384 + ldsB1);  \
} while(0)
#define RDA_(B2, q, mi, ks) (*(const bf16x8*)(AsB + (B2)*32768 + aBase + (q)*4096 + (mi)*2048 + koff[ks]))
#define RDB_(B2, ni, ks)    (*(const bf16x8*)(BsB + (B2)*32768 + bBase + (ni)*2048 + koff[ks]))
#define BAR() __builtin_amdgcn_s_barrier()

__global__ __launch_bounds__(512, 2) void k_gemm(const unsigned short* __restrict__ xbf,
                                                 const unsigned short* __restrict__ wbf,
                                                 const unsigned short* __restrict__ interbf,
                                                 const unsigned short* __restrict__ abf,
                                                 const float* __restrict__ bias,
                                                 float* __restrict__ out) {
  __shared__ unsigned short As[2][2][8192];
  __shared__ unsigned short Bs[2][2][8192];
  const int tid  = threadIdx.x;
  const int lane = tid & 63;
  const int wid  = tid >> 6;     // 0..7
  const int wm   = wid >> 2;     // 0..1
  const int wn   = wid & 3;      // 0..3
  const int l15  = lane & 15;
  const int hi   = lane >> 4;
  const int swz  = l15 & 7;

  // XCD-aware bijective swizzle: grid 512 = 64 mt x 8 nt
  int bid  = blockIdx.x;
  int swzb = ((bid & 7) << 6) | (bid >> 3);
  const int mt = swzb >> 3;
  const int nt = swzb & 7;
  const int mrow0 = mt << 8;
  const int ncol0 = nt << 8;
  const int bb = mrow0 >> 11;

  const int m0 = mrow0 + wm * 128;
  const int n0 = ncol0 + wn * 64;

  const unsigned short* Ag = xbf + (size_t)mrow0 * K_TOT;
  const unsigned short* Bg = wbf + (size_t)ncol0 * K_TOT;
  char* AsB = (char*)As;
  char* BsB = (char*)Bs;

  // staging offsets (pre-swizzled source; linear LDS dest)
  const int r0    = tid >> 3;
  const int k80   = (tid & 7) ^ (r0 & 7);
  const int gOff0 = r0 * K_TOT + k80 * 8;
  const int gOff1 = gOff0 + 64 * K_TOT;
  const int ldsB0 = wid * 1024;
  const int ldsB1 = 8192 + wid * 1024;

  // fragment read bases (byte offsets)
  const int aBase = wm * 16384 + l15 * 128;
  const int bBase = (wn >> 1) * 16384 + (wn & 1) * 8192 + l15 * 128;
  int koff[2];
  koff[0] = ((0 * 4 + hi) ^ swz) * 16;
  koff[1] = ((1 * 4 + hi) ^ swz) * 16;

  floatx4 acc[8][4];
  bf16x8 bfr[4][2];   // B-frags: held for a whole K-tile
  bf16x8 af[2][2];    // A-subtile: fresh each phase

  // ---- prologue: LoRA acc-init + stage 6 half-tiles ----
  {
    bf16x8 la[8], lb[4];
    #pragma unroll
    for (int mi = 0; mi < 8; ++mi)
      la[mi] = *(const bf16x8*)(interbf + (size_t)(m0 + mi * 16 + l15) * 32 + hi * 8);
    #pragma unroll
    for (int ni = 0; ni < 4; ++ni)
      lb[ni] = *(const bf16x8*)(abf + ((size_t)bb * N_TOT + n0 + ni * 16 + l15) * 32 + hi * 8);

    STAGE_A(0, 0, 0); STAGE_A(0, 1, 0); STAGE_B(0, 0, 0); STAGE_B(0, 1, 0);
    STAGE_B(1, 0, 1); STAGE_B(1, 1, 1);

    floatx4 z = {0.f, 0.f, 0.f, 0.f};
    #pragma unroll
    for (int mi = 0; mi < 8; ++mi)
      #pragma unroll
      for (int ni = 0; ni < 4; ++ni)
        acc[mi][ni] = __builtin_amdgcn_mfma_f32_16x16x32_bf16(la[mi], lb[ni], z, 0, 0, 0);
  }
  asm volatile("s_waitcnt vmcnt(4)" ::: "memory");   // t0's 4 halves landed; t1's B pair in flight
  BAR();

  auto tile_step = [&](int t, auto bufc, auto sac, auto sbc, auto vmc) {
    constexpr int BUF = decltype(bufc)::value;
    constexpr int SA  = decltype(sac)::value;   // stage A0,A1(t+1) -> BUF^1 at ph1,ph2
    constexpr int SB  = decltype(sbc)::value;   // stage B0,B1(t+2) -> BUF at ph3,ph4
    constexpr int VM  = decltype(vmc)::value;   // ph4-end vmcnt: 4, 0, or -1

    // ---- ph1: read B-all(8) + A-sub q0(4); stage A0(t+1); MFMA q0
    #pragma unroll
    for (int ni = 0; ni < 4; ++ni) { bfr[ni][0] = RDB_(BUF, ni, 0); bfr[ni][1] = RDB_(BUF, ni, 1); }
    #pragma unroll
    for (int mi = 0; mi < 2; ++mi) { af[mi][0] = RDA_(BUF, 0, mi, 0); af[mi][1] = RDA_(BUF, 0, mi, 1); }
    if constexpr (SA) STAGE_A(BUF ^ 1, 0, t + 1);
    BAR();
    __builtin_amdgcn_s_setprio(1);
    #pragma unroll
    for (int mi = 0; mi < 2; ++mi)
      #pragma unroll
      for (int ni = 0; ni < 4; ++ni) {
        acc[mi][ni] = __builtin_amdgcn_mfma_f32_16x16x32_bf16(af[mi][0], bfr[ni][0], acc[mi][ni], 0, 0, 0);
        acc[mi][ni] = __builtin_amdgcn_mfma_f32_16x16x32_bf16(af[mi][1], bfr[ni][1], acc[mi][ni], 0, 0, 0);
      }
    __builtin_amdgcn_s_setprio(0);
    BAR();

    // ---- ph2: read A-sub q1; stage A1(t+1); MFMA q1
    #pragma unroll
    for (int mi = 0; mi < 2; ++mi) { af[mi][0] = RDA_(BUF, 1, mi, 0); af[mi][1] = RDA_(BUF, 1, mi, 1); }
    if constexpr (SA) STAGE_A(BUF ^ 1, 1, t + 1);
    BAR();
    __builtin_amdgcn_s_setprio(1);
    #pragma unroll
    for (int mi = 0; mi < 2; ++mi)
      #pragma unroll
      for (int ni = 0; ni < 4; ++ni) {
        acc[2+mi][ni] = __builtin_amdgcn_mfma_f32_16x16x32_bf16(af[mi][0], bfr[ni][0], acc[2+mi][ni], 0, 0, 0);
        acc[2+mi][ni] = __builtin_amdgcn_mfma_f32_16x16x32_bf16(af[mi][1], bfr[ni][1], acc[2+mi][ni], 0, 0, 0);
      }
    __builtin_amdgcn_s_setprio(0);
    BAR();

    // ---- ph3: read A-sub q2; stage B0(t+2) (B(buf) dead after ph1); MFMA q2
    #pragma unroll
    for (int mi = 0; mi < 2; ++mi) { af[mi][0] = RDA_(BUF, 2, mi, 0); af[mi][1] = RDA_(BUF, 2, mi, 1); }
    if constexpr (SB) STAGE_B(BUF, 0, t + 2);
    BAR();
    __builtin_amdgcn_s_setprio(1);
    #pragma unroll
    for (int mi = 0; mi < 2; ++mi)
      #pragma unroll
      for (int ni = 0; ni < 4; ++ni) {
        acc[4+mi][ni] = __builtin_amdgcn_mfma_f32_16x16x32_bf16(af[mi][0], bfr[ni][0], acc[4+mi][ni], 0, 0, 0);
        acc[4+mi][ni] = __builtin_amdgcn_mfma_f32_16x16x32_bf16(af[mi][1], bfr[ni][1], acc[4+mi][ni], 0, 0, 0);
      }
    __builtin_amdgcn_s_setprio(0);
    BAR();

    // ---- ph4: read A-sub q3; stage B1(t+2); MFMA q3; vmcnt at end
    #pragma unroll
    for (int mi = 0; mi < 2; ++mi) { af[mi][0] = RDA_(BUF, 3, mi, 0); af[mi][1] = RDA_(BUF, 3, mi, 1); }
    if constexpr (SB) STAGE_B(BUF, 1, t + 2);
    BAR();
    __builtin_amdgcn_s_setprio(1);
    #pragma unroll
    for (int mi = 0; mi < 2; ++mi)
      #pragma unroll
      for (int ni = 0; ni < 4; ++ni) {
        acc[6+mi][ni] = __builtin_amdgcn_mfma_f32_16x16x32_bf16(af[mi][0], bfr[ni][0], acc[6+mi][ni], 0, 0, 0);
        acc[6+mi][ni] = __builtin_amdgcn_mfma_f32_16x16x32_bf16(af[mi][1], bfr[ni][1], acc[6+mi][ni], 0, 0, 0);
      }
    __builtin_amdgcn_s_setprio(0);
    if constexpr (VM == 4)      asm volatile("s_waitcnt vmcnt(4)" ::: "memory");
    else if constexpr (VM == 0) asm volatile("s_waitcnt vmcnt(0)" ::: "memory");
    BAR();
  };

  for (int t = 0; t < NT - 2; t += 2) {
    tile_step(t,     IC<0>{}, IC<1>{}, IC<1>{}, IC<4>{});
    tile_step(t + 1, IC<1>{}, IC<1>{}, IC<1>{}, IC<4>{});
  }
  tile_step(NT - 2, IC<0>{}, IC<1>{}, IC<0>{}, IC<0>{});
  tile_step(NT - 1, IC<1>{}, IC<0>{}, IC<0>{}, IC<-1>{});

  // ---- epilogue: + bias, store f32 ----
  #pragma unroll
  for (int ni = 0; ni < 4; ++ni) {
    int col = n0 + ni * 16 + l15;
    float bv = bias[col];
    #pragma unroll
    for (int mi = 0; mi < 8; ++mi) {
      int r = m0 + mi * 16 + hi * 4;
      #pragma unroll
      for (int j = 0; j < 4; ++j)
        out[(size_t)(r + j) * N_TOT + col] = acc[mi][ni][j] + bv;
    }
  }
}

// ---------------- launcher ----------------
extern "C" void kernel_launch(void* const* d_in, const int* in_sizes, int n_in,
                              void* d_out, int out_size, void* d_ws, size_t ws_size,
                              hipStream_t stream) {
  const float* x    = (const float*)d_in[0];   // [8,2048,2048]
  const float* Ap   = (const float*)d_in[1];   // [8,2048,16]
  const float* Bp   = (const float*)d_in[2];   // [8,16,2048]
  const float* W    = (const float*)d_in[3];   // [2048,2048]
  const float* bias = (const float*)d_in[4];   // [2048]
  float* out = (float*)d_out;

  char* ws = (char*)d_ws;
  unsigned short* xbf     = (unsigned short*)(ws);                        // 64 MiB
  unsigned short* wbf     = (unsigned short*)(ws + 67108864);             // 8 MiB
  unsigned short* abf     = (unsigned short*)(ws + 67108864 + 8388608);   // 1 MiB
  unsigned short* interbf = (unsigned short*)(ws + 67108864 + 8388608 + 1048576); // 1 MiB

  k_convert_small<<<dim3(2112), dim3(256), 0, stream>>>(W, Ap, wbf, abf);
  k_xinter<<<dim3(1024), dim3(512), 0, stream>>>(x, Bp, xbf, interbf);
  k_gemm<<<dim3(512), dim3(512), 0, stream>>>(xbf, wbf, interbf, abf, bias, out);
}

// Round 10
// 192.726 us; speedup vs baseline: 1.2113x; 1.0009x over previous
//
#include <hip/hip_runtime.h>
#include <cstdint>
#include <cstddef>

// ---------------- types ----------------
typedef __attribute__((ext_vector_type(4))) float  floatx4;
typedef __attribute__((ext_vector_type(8))) __bf16 bf16x8;
typedef __attribute__((ext_vector_type(8))) unsigned short u16x8;

#define M_TOT 16384   // B*S
#define N_TOT 2048    // D_OUT
#define K_TOT 2048    // D_IN
#define NBATCH 8
#define RLORA 16
#define NT 32         // K tiles of 64

// f32 -> bf16 round-to-nearest-even
__device__ __forceinline__ unsigned short f32_to_bf16(float f) {
  unsigned u = __float_as_uint(f);
  u += 0x7fffu + ((u >> 16) & 1u);
  return (unsigned short)(u >> 16);
}

__device__ __forceinline__ u16x8 cvt8(const float4& a, const float4& b) {
  u16x8 o;
  o[0] = f32_to_bf16(a.x); o[1] = f32_to_bf16(a.y);
  o[2] = f32_to_bf16(a.z); o[3] = f32_to_bf16(a.w);
  o[4] = f32_to_bf16(b.x); o[5] = f32_to_bf16(b.y);
  o[6] = f32_to_bf16(b.z); o[7] = f32_to_bf16(b.w);
  return o;
}

// async global->LDS, 16B per lane (LDS dest wave-uniform base + lane*16)
#define GLOAD_LDS16(gp, lp)                                                        \
  __builtin_amdgcn_global_load_lds((__attribute__((address_space(1))) void*)(void*)(gp), \
                                   (__attribute__((address_space(3))) void*)(void*)(lp), \
                                   16, 0, 0)

template<int V> struct IC { static constexpr int value = V; };

// ---------------- combined small converts: W (2048 blocks) | A_params pack (64 blocks) ----------------
__global__ void k_convert_small(const float* __restrict__ W, const float* __restrict__ Ap,
                                unsigned short* __restrict__ wbf, unsigned short* __restrict__ abf) {
  int b = blockIdx.x;
  if (b < 2048) {
    int i = b * 256 + threadIdx.x;
    const float4* p = (const float4*)W + (size_t)i * 2;
    *(u16x8*)(wbf + (size_t)i * 8) = cvt8(p[0], p[1]);
  } else {
    int row = (b - 2048) * 256 + threadIdx.x;
    const float4* p = (const float4*)(Ap + (size_t)row * RLORA);
    u16x8 lo = cvt8(p[0], p[1]), hi2 = cvt8(p[2], p[3]), z = {0,0,0,0,0,0,0,0};
    u16x8* dst = (u16x8*)(abf + (size_t)row * 32);
    dst[0] = lo; dst[1] = hi2; dst[2] = z; dst[3] = z;
  }
}

// ---------------- fused: xbf = bf16(x) AND inter = x @ Bp^T ----------------
// 1024 blocks x 256 thr; block = 16 rows (one m-tile); 4 waves split K (512 each).
// The f32 x load IS the MFMA A-fragment (row=l15, k=hi*8+j). Bp (2 MiB f32) is L2-resident.
__global__ __launch_bounds__(256) void k_xinter(const float* __restrict__ x,
                                                const float* __restrict__ Bp,
                                                unsigned short* __restrict__ xbf,
                                                unsigned short* __restrict__ interbf) {
  const int tid  = threadIdx.x;
  const int lane = tid & 63;
  const int wv   = tid >> 6;
  const int l15  = lane & 15;
  const int hi   = lane >> 4;
  const int m0   = blockIdx.x * 16;
  const int bb   = m0 >> 11;

  floatx4 acc = {0.f, 0.f, 0.f, 0.f};
  const float* bpb = Bp + (size_t)bb * (RLORA * K_TOT);
  const size_t xrow = (size_t)(m0 + l15) * K_TOT;
  const size_t brow = (size_t)l15 * K_TOT;
  const int kb0 = wv * 512;
  for (int kb = kb0; kb < kb0 + 512; kb += 32) {
    const float* xp = x + xrow + kb + hi * 8;
    u16x8 ao = cvt8(*(const float4*)xp, *(const float4*)(xp + 4));
    *(u16x8*)(xbf + xrow + kb + hi * 8) = ao;
    const float* bpp = bpb + brow + kb + hi * 8;
    u16x8 bo = cvt8(*(const float4*)bpp, *(const float4*)(bpp + 4));
    acc = __builtin_amdgcn_mfma_f32_16x16x32_bf16(*(bf16x8*)&ao, *(bf16x8*)&bo, acc, 0, 0, 0);
  }

  __shared__ floatx4 red[4][64];
  red[wv][lane] = acc;
  __syncthreads();
  if (wv == 0) {
    floatx4 s = red[0][lane] + red[1][lane] + red[2][lane] + red[3][lane];
    #pragma unroll
    for (int j = 0; j < 4; ++j) {
      int m = m0 + hi * 4 + j;          // C/D layout: row = hi*4+j, col = l15 = r
      interbf[(size_t)m * 32 + l15] = f32_to_bf16(s[j]);
      interbf[(size_t)m * 32 + 16 + l15] = 0;
    }
  }
}

// ---------------- main GEMM: 256x256, BK=64, 8 waves, 8-phase (R7 exact — session best) ----------------
#define STAGE_A(bufi, h, tt) do {                                                      \
  GLOAD_LDS16(Ag + (h)*262144 + (tt)*64 + gOff0, AsB + ((bufi)*2+(h))*16384 + ldsB0);  \
  GLOAD_LDS16(Ag + (h)*262144 + (tt)*64 + gOff1, AsB + ((bufi)*2+(h))*16384 + ldsB1);  \
} while(0)
#define STAGE_B(bufi, h, tt) do {                                                      \
  GLOAD_LDS16(Bg + (h)*262144 + (tt)*64 + gOff0, BsB + ((bufi)*2+(h))*16384 + ldsB0);  \
  GLOAD_LDS16(Bg + (h)*262144 + (tt)*64 + gOff1, BsB + ((bufi)*2+(h))*16384 + ldsB1);  \
} while(0)
#define RDA_(B2, q, mi, ks) (*(const bf16x8*)(AsB + (B2)*32768 + aBase + (q)*4096 + (mi)*2048 + koff[ks]))
#define RDB_(B2, ni, ks)    (*(const bf16x8*)(BsB + (B2)*32768 + bBase + (ni)*2048 + koff[ks]))
#define BAR() __builtin_amdgcn_s_barrier()

__global__ __launch_bounds__(512, 2) void k_gemm(const unsigned short* __restrict__ xbf,
                                                 const unsigned short* __restrict__ wbf,
                                                 const unsigned short* __restrict__ interbf,
                                                 const unsigned short* __restrict__ abf,
                                                 const float* __restrict__ bias,
                                                 float* __restrict__ out) {
  __shared__ unsigned short As[2][2][8192];
  __shared__ unsigned short Bs[2][2][8192];
  const int tid  = threadIdx.x;
  const int lane = tid & 63;
  const int wid  = tid >> 6;     // 0..7
  const int wm   = wid >> 2;     // 0..1
  const int wn   = wid & 3;      // 0..3
  const int l15  = lane & 15;
  const int hi   = lane >> 4;
  const int swz  = l15 & 7;

  // XCD-aware bijective swizzle: grid 512 = 64 mt x 8 nt
  int bid  = blockIdx.x;
  int swzb = ((bid & 7) << 6) | (bid >> 3);
  const int mt = swzb >> 3;
  const int nt = swzb & 7;
  const int mrow0 = mt << 8;
  const int ncol0 = nt << 8;
  const int bb = mrow0 >> 11;

  const int m0 = mrow0 + wm * 128;
  const int n0 = ncol0 + wn * 64;

  const unsigned short* Ag = xbf + (size_t)mrow0 * K_TOT;
  const unsigned short* Bg = wbf + (size_t)ncol0 * K_TOT;
  char* AsB = (char*)As;
  char* BsB = (char*)Bs;

  // staging offsets (pre-swizzled source; linear LDS dest)
  const int r0    = tid >> 3;
  const int k80   = (tid & 7) ^ (r0 & 7);
  const int gOff0 = r0 * K_TOT + k80 * 8;
  const int gOff1 = gOff0 + 64 * K_TOT;
  const int ldsB0 = wid * 1024;
  const int ldsB1 = 8192 + wid * 1024;

  // fragment read bases (byte offsets)
  const int aBase = wm * 16384 + l15 * 128;
  const int bBase = (wn >> 1) * 16384 + (wn & 1) * 8192 + l15 * 128;
  int koff[2];
  koff[0] = ((0 * 4 + hi) ^ swz) * 16;
  koff[1] = ((1 * 4 + hi) ^ swz) * 16;

  floatx4 acc[8][4];
  bf16x8 bfr[4][2];   // B-frags: held for a whole K-tile
  bf16x8 af[2][2];    // A-subtile: fresh each phase

  // ---- prologue: LoRA acc-init + stage 6 half-tiles ----
  {
    bf16x8 la[8], lb[4];
    #pragma unroll
    for (int mi = 0; mi < 8; ++mi)
      la[mi] = *(const bf16x8*)(interbf + (size_t)(m0 + mi * 16 + l15) * 32 + hi * 8);
    #pragma unroll
    for (int ni = 0; ni < 4; ++ni)
      lb[ni] = *(const bf16x8*)(abf + ((size_t)bb * N_TOT + n0 + ni * 16 + l15) * 32 + hi * 8);

    STAGE_A(0, 0, 0); STAGE_A(0, 1, 0); STAGE_B(0, 0, 0); STAGE_B(0, 1, 0);
    STAGE_B(1, 0, 1); STAGE_B(1, 1, 1);

    floatx4 z = {0.f, 0.f, 0.f, 0.f};
    #pragma unroll
    for (int mi = 0; mi < 8; ++mi)
      #pragma unroll
      for (int ni = 0; ni < 4; ++ni)
        acc[mi][ni] = __builtin_amdgcn_mfma_f32_16x16x32_bf16(la[mi], lb[ni], z, 0, 0, 0);
  }
  asm volatile("s_waitcnt vmcnt(4)" ::: "memory");   // t0's 4 halves landed; t1's B pair in flight
  BAR();

  auto tile_step = [&](int t, auto bufc, auto sac, auto sbc, auto vmc) {
    constexpr int BUF = decltype(bufc)::value;
    constexpr int SA  = decltype(sac)::value;   // stage A0,A1(t+1) -> BUF^1 at ph1,ph2
    constexpr int SB  = decltype(sbc)::value;   // stage B0,B1(t+2) -> BUF at ph3,ph4
    constexpr int VM  = decltype(vmc)::value;   // ph4-end vmcnt: 4, 0, or -1

    // ---- ph1: read B-all(8) + A-sub q0(4); stage A0(t+1); MFMA q0
    #pragma unroll
    for (int ni = 0; ni < 4; ++ni) { bfr[ni][0] = RDB_(BUF, ni, 0); bfr[ni][1] = RDB_(BUF, ni, 1); }
    #pragma unroll
    for (int mi = 0; mi < 2; ++mi) { af[mi][0] = RDA_(BUF, 0, mi, 0); af[mi][1] = RDA_(BUF, 0, mi, 1); }
    if constexpr (SA) STAGE_A(BUF ^ 1, 0, t + 1);
    BAR();
    __builtin_amdgcn_s_setprio(1);
    #pragma unroll
    for (int mi = 0; mi < 2; ++mi)
      #pragma unroll
      for (int ni = 0; ni < 4; ++ni) {
        acc[mi][ni] = __builtin_amdgcn_mfma_f32_16x16x32_bf16(af[mi][0], bfr[ni][0], acc[mi][ni], 0, 0, 0);
        acc[mi][ni] = __builtin_amdgcn_mfma_f32_16x16x32_bf16(af[mi][1], bfr[ni][1], acc[mi][ni], 0, 0, 0);
      }
    __builtin_amdgcn_s_setprio(0);
    BAR();

    // ---- ph2: read A-sub q1; stage A1(t+1); MFMA q1
    #pragma unroll
    for (int mi = 0; mi < 2; ++mi) { af[mi][0] = RDA_(BUF, 1, mi, 0); af[mi][1] = RDA_(BUF, 1, mi, 1); }
    if constexpr (SA) STAGE_A(BUF ^ 1, 1, t + 1);
    BAR();
    __builtin_amdgcn_s_setprio(1);
    #pragma unroll
    for (int mi = 0; mi < 2; ++mi)
      #pragma unroll
      for (int ni = 0; ni < 4; ++ni) {
        acc[2+mi][ni] = __builtin_amdgcn_mfma_f32_16x16x32_bf16(af[mi][0], bfr[ni][0], acc[2+mi][ni], 0, 0, 0);
        acc[2+mi][ni] = __builtin_amdgcn_mfma_f32_16x16x32_bf16(af[mi][1], bfr[ni][1], acc[2+mi][ni], 0, 0, 0);
      }
    __builtin_amdgcn_s_setprio(0);
    BAR();

    // ---- ph3: read A-sub q2; stage B0(t+2) (B(buf) dead after ph1); MFMA q2
    #pragma unroll
    for (int mi = 0; mi < 2; ++mi) { af[mi][0] = RDA_(BUF, 2, mi, 0); af[mi][1] = RDA_(BUF, 2, mi, 1); }
    if constexpr (SB) STAGE_B(BUF, 0, t + 2);
    BAR();
    __builtin_amdgcn_s_setprio(1);
    #pragma unroll
    for (int mi = 0; mi < 2; ++mi)
      #pragma unroll
      for (int ni = 0; ni < 4; ++ni) {
        acc[4+mi][ni] = __builtin_amdgcn_mfma_f32_16x16x32_bf16(af[mi][0], bfr[ni][0], acc[4+mi][ni], 0, 0, 0);
        acc[4+mi][ni] = __builtin_amdgcn_mfma_f32_16x16x32_bf16(af[mi][1], bfr[ni][1], acc[4+mi][ni], 0, 0, 0);
      }
    __builtin_amdgcn_s_setprio(0);
    BAR();

    // ---- ph4: read A-sub q3; stage B1(t+2); MFMA q3; vmcnt at end
    #pragma unroll
    for (int mi = 0; mi < 2; ++mi) { af[mi][0] = RDA_(BUF, 3, mi, 0); af[mi][1] = RDA_(BUF, 3, mi, 1); }
    if constexpr (SB) STAGE_B(BUF, 1, t + 2);
    BAR();
    __builtin_amdgcn_s_setprio(1);
    #pragma unroll
    for (int mi = 0; mi < 2; ++mi)
      #pragma unroll
      for (int ni = 0; ni < 4; ++ni) {
        acc[6+mi][ni] = __builtin_amdgcn_mfma_f32_16x16x32_bf16(af[mi][0], bfr[ni][0], acc[6+mi][ni], 0, 0, 0);
        acc[6+mi][ni] = __builtin_amdgcn_mfma_f32_16x16x32_bf16(af[mi][1], bfr[ni][1], acc[6+mi][ni], 0, 0, 0);
      }
    __builtin_amdgcn_s_setprio(0);
    if constexpr (VM == 4)      asm volatile("s_waitcnt vmcnt(4)" ::: "memory");
    else if constexpr (VM == 0) asm volatile("s_waitcnt vmcnt(0)" ::: "memory");
    BAR();
  };

  for (int t = 0; t < NT - 2; t += 2) {
    tile_step(t,     IC<0>{}, IC<1>{}, IC<1>{}, IC<4>{});
    tile_step(t + 1, IC<1>{}, IC<1>{}, IC<1>{}, IC<4>{});
  }
  tile_step(NT - 2, IC<0>{}, IC<1>{}, IC<0>{}, IC<0>{});
  tile_step(NT - 1, IC<1>{}, IC<0>{}, IC<0>{}, IC<-1>{});

  // ---- epilogue: + bias, store f32 ----
  #pragma unroll
  for (int ni = 0; ni < 4; ++ni) {
    int col = n0 + ni * 16 + l15;
    float bv = bias[col];
    #pragma unroll
    for (int mi = 0; mi < 8; ++mi) {
      int r = m0 + mi * 16 + hi * 4;
      #pragma unroll
      for (int j = 0; j < 4; ++j)
        out[(size_t)(r + j) * N_TOT + col] = acc[mi][ni][j] + bv;
    }
  }
}

// ---------------- launcher ----------------
extern "C" void kernel_launch(void* const* d_in, const int* in_sizes, int n_in,
                              void* d_out, int out_size, void* d_ws, size_t ws_size,
                              hipStream_t stream) {
  const float* x    = (const float*)d_in[0];   // [8,2048,2048]
  const float* Ap   = (const float*)d_in[1];   // [8,2048,16]
  const float* Bp   = (const float*)d_in[2];   // [8,16,2048]
  const float* W    = (const float*)d_in[3];   // [2048,2048]
  const float* bias = (const float*)d_in[4];   // [2048]
  float* out = (float*)d_out;

  char* ws = (char*)d_ws;
  unsigned short* xbf     = (unsigned short*)(ws);                        // 64 MiB
  unsigned short* wbf     = (unsigned short*)(ws + 67108864);             // 8 MiB
  unsigned short* abf     = (unsigned short*)(ws + 67108864 + 8388608);   // 1 MiB
  unsigned short* interbf = (unsigned short*)(ws + 67108864 + 8388608 + 1048576); // 1 MiB

  k_convert_small<<<dim3(2112), dim3(256), 0, stream>>>(W, Ap, wbf, abf);
  k_xinter<<<dim3(1024), dim3(256), 0, stream>>>(x, Bp, xbf, interbf);
  k_gemm<<<dim3(512), dim3(512), 0, stream>>>(xbf, wbf, interbf, abf, bias, out);
}

// Round 11
// 188.946 us; speedup vs baseline: 1.2356x; 1.0200x over previous
//
#include <hip/hip_runtime.h>
#include <cstdint>
#include <cstddef>

// ---------------- types ----------------
typedef __attribute__((ext_vector_type(4))) float  floatx4;
typedef __attribute__((ext_vector_type(8))) __bf16 bf16x8;
typedef __attribute__((ext_vector_type(8))) unsigned short u16x8;

#define M_TOT 16384   // B*S
#define N_TOT 2048    // D_OUT
#define K_TOT 2048    // D_IN
#define NBATCH 8
#define RLORA 16
#define NT 32         // K tiles of 64

// f32 -> bf16 round-to-nearest-even
__device__ __forceinline__ unsigned short f32_to_bf16(float f) {
  unsigned u = __float_as_uint(f);
  u += 0x7fffu + ((u >> 16) & 1u);
  return (unsigned short)(u >> 16);
}

__device__ __forceinline__ u16x8 cvt8(const float4& a, const float4& b) {
  u16x8 o;
  o[0] = f32_to_bf16(a.x); o[1] = f32_to_bf16(a.y);
  o[2] = f32_to_bf16(a.z); o[3] = f32_to_bf16(a.w);
  o[4] = f32_to_bf16(b.x); o[5] = f32_to_bf16(b.y);
  o[6] = f32_to_bf16(b.z); o[7] = f32_to_bf16(b.w);
  return o;
}

// async global->LDS, 16B per lane (LDS dest wave-uniform base + lane*16)
#define GLOAD_LDS16(gp, lp)                                                        \
  __builtin_amdgcn_global_load_lds((__attribute__((address_space(1))) void*)(void*)(gp), \
                                   (__attribute__((address_space(3))) void*)(void*)(lp), \
                                   16, 0, 0)

template<int V> struct IC { static constexpr int value = V; };

// ---------------- merged prep (ONE launch): xinter FIRST, then Ap pack, then W convert ----------------
// b in [0,1024):    xinter block (16 rows, 4 waves split K): xbf=bf16(x), inter=x@Bp^T
// b in [1024,1088): Ap pack [8*2048][16] -> [8*2048][32] zero-padded
// b in [1088,3136): W convert (8 elems/thread)
// Long xinter blocks dispatch first and saturate the machine; short W/Ap blocks backfill
// idle slots during xinter's tail (inverse of R8's failed W-first ordering).
__global__ __launch_bounds__(256) void k_prep(const float* __restrict__ x, const float* __restrict__ Bp,
                                              const float* __restrict__ W, const float* __restrict__ Ap,
                                              unsigned short* __restrict__ xbf, unsigned short* __restrict__ interbf,
                                              unsigned short* __restrict__ wbf, unsigned short* __restrict__ abf) {
  __shared__ floatx4 red[4][64];
  const int b   = blockIdx.x;
  const int tid = threadIdx.x;

  if (b < 1024) {
    // ---- xinter: block = 16 rows (one m-tile); 4 waves split K (512 each).
    // The f32 x load IS the MFMA A-fragment (row=l15, k=hi*8+j). Bp (2 MiB f32) is L2-resident.
    const int lane = tid & 63;
    const int wv   = tid >> 6;
    const int l15  = lane & 15;
    const int hi   = lane >> 4;
    const int m0   = b * 16;
    const int bb   = m0 >> 11;

    floatx4 acc = {0.f, 0.f, 0.f, 0.f};
    const float* bpb = Bp + (size_t)bb * (RLORA * K_TOT);
    const size_t xrow = (size_t)(m0 + l15) * K_TOT;
    const size_t brow = (size_t)l15 * K_TOT;
    const int kb0 = wv * 512;
    for (int kb = kb0; kb < kb0 + 512; kb += 32) {
      const float* xp = x + xrow + kb + hi * 8;
      u16x8 ao = cvt8(*(const float4*)xp, *(const float4*)(xp + 4));
      *(u16x8*)(xbf + xrow + kb + hi * 8) = ao;
      const float* bpp = bpb + brow + kb + hi * 8;
      u16x8 bo = cvt8(*(const float4*)bpp, *(const float4*)(bpp + 4));
      acc = __builtin_amdgcn_mfma_f32_16x16x32_bf16(*(bf16x8*)&ao, *(bf16x8*)&bo, acc, 0, 0, 0);
    }

    red[wv][lane] = acc;
    __syncthreads();
    if (wv == 0) {
      floatx4 s = red[0][lane] + red[1][lane] + red[2][lane] + red[3][lane];
      #pragma unroll
      for (int j = 0; j < 4; ++j) {
        int m = m0 + hi * 4 + j;          // C/D layout: row = hi*4+j, col = l15 = r
        interbf[(size_t)m * 32 + l15] = f32_to_bf16(s[j]);
        interbf[(size_t)m * 32 + 16 + l15] = 0;
      }
    }
    return;
  }
  if (b < 1088) {
    // ---- Ap pack: [16384][16] f32 -> [16384][32] bf16 zero-padded
    int row = (b - 1024) * 256 + tid;
    const float4* p = (const float4*)(Ap + (size_t)row * RLORA);
    u16x8 lo = cvt8(p[0], p[1]), hi2 = cvt8(p[2], p[3]), z = {0,0,0,0,0,0,0,0};
    u16x8* dst = (u16x8*)(abf + (size_t)row * 32);
    dst[0] = lo; dst[1] = hi2; dst[2] = z; dst[3] = z;
    return;
  }
  // ---- W convert: 2048 blocks x 256 thr x 8 elems
  int i = (b - 1088) * 256 + tid;
  const float4* p = (const float4*)W + (size_t)i * 2;
  *(u16x8*)(wbf + (size_t)i * 8) = cvt8(p[0], p[1]);
}

// ---------------- main GEMM: 256x256, BK=64, 8 waves, 8-phase (R7 exact — session best) ----------------
#define STAGE_A(bufi, h, tt) do {                                                      \
  GLOAD_LDS16(Ag + (h)*262144 + (tt)*64 + gOff0, AsB + ((bufi)*2+(h))*16384 + ldsB0);  \
  GLOAD_LDS16(Ag + (h)*262144 + (tt)*64 + gOff1, AsB + ((bufi)*2+(h))*16384 + ldsB1);  \
} while(0)
#define STAGE_B(bufi, h, tt) do {                                                      \
  GLOAD_LDS16(Bg + (h)*262144 + (tt)*64 + gOff0, BsB + ((bufi)*2+(h))*16384 + ldsB0);  \
  GLOAD_LDS16(Bg + (h)*262144 + (tt)*64 + gOff1, BsB + ((bufi)*2+(h))*16384 + ldsB1);  \
} while(0)
#define RDA_(B2, q, mi, ks) (*(const bf16x8*)(AsB + (B2)*32768 + aBase + (q)*4096 + (mi)*2048 + koff[ks]))
#define RDB_(B2, ni, ks)    (*(const bf16x8*)(BsB + (B2)*32768 + bBase + (ni)*2048 + koff[ks]))
#define BAR() __builtin_amdgcn_s_barrier()

__global__ __launch_bounds__(512, 2) void k_gemm(const unsigned short* __restrict__ xbf,
                                                 const unsigned short* __restrict__ wbf,
                                                 const unsigned short* __restrict__ interbf,
                                                 const unsigned short* __restrict__ abf,
                                                 const float* __restrict__ bias,
                                                 float* __restrict__ out) {
  __shared__ unsigned short As[2][2][8192];
  __shared__ unsigned short Bs[2][2][8192];
  const int tid  = threadIdx.x;
  const int lane = tid & 63;
  const int wid  = tid >> 6;     // 0..7
  const int wm   = wid >> 2;     // 0..1
  const int wn   = wid & 3;      // 0..3
  const int l15  = lane & 15;
  const int hi   = lane >> 4;
  const int swz  = l15 & 7;

  // XCD-aware bijective swizzle: grid 512 = 64 mt x 8 nt
  int bid  = blockIdx.x;
  int swzb = ((bid & 7) << 6) | (bid >> 3);
  const int mt = swzb >> 3;
  const int nt = swzb & 7;
  const int mrow0 = mt << 8;
  const int ncol0 = nt << 8;
  const int bb = mrow0 >> 11;

  const int m0 = mrow0 + wm * 128;
  const int n0 = ncol0 + wn * 64;

  const unsigned short* Ag = xbf + (size_t)mrow0 * K_TOT;
  const unsigned short* Bg = wbf + (size_t)ncol0 * K_TOT;
  char* AsB = (char*)As;
  char* BsB = (char*)Bs;

  // staging offsets (pre-swizzled source; linear LDS dest)
  const int r0    = tid >> 3;
  const int k80   = (tid & 7) ^ (r0 & 7);
  const int gOff0 = r0 * K_TOT + k80 * 8;
  const int gOff1 = gOff0 + 64 * K_TOT;
  const int ldsB0 = wid * 1024;
  const int ldsB1 = 8192 + wid * 1024;

  // fragment read bases (byte offsets)
  const int aBase = wm * 16384 + l15 * 128;
  const int bBase = (wn >> 1) * 16384 + (wn & 1) * 8192 + l15 * 128;
  int koff[2];
  koff[0] = ((0 * 4 + hi) ^ swz) * 16;
  koff[1] = ((1 * 4 + hi) ^ swz) * 16;

  floatx4 acc[8][4];
  bf16x8 bfr[4][2];   // B-frags: held for a whole K-tile
  bf16x8 af[2][2];    // A-subtile: fresh each phase

  // ---- prologue: LoRA acc-init + stage 6 half-tiles ----
  {
    bf16x8 la[8], lb[4];
    #pragma unroll
    for (int mi = 0; mi < 8; ++mi)
      la[mi] = *(const bf16x8*)(interbf + (size_t)(m0 + mi * 16 + l15) * 32 + hi * 8);
    #pragma unroll
    for (int ni = 0; ni < 4; ++ni)
      lb[ni] = *(const bf16x8*)(abf + ((size_t)bb * N_TOT + n0 + ni * 16 + l15) * 32 + hi * 8);

    STAGE_A(0, 0, 0); STAGE_A(0, 1, 0); STAGE_B(0, 0, 0); STAGE_B(0, 1, 0);
    STAGE_B(1, 0, 1); STAGE_B(1, 1, 1);

    floatx4 z = {0.f, 0.f, 0.f, 0.f};
    #pragma unroll
    for (int mi = 0; mi < 8; ++mi)
      #pragma unroll
      for (int ni = 0; ni < 4; ++ni)
        acc[mi][ni] = __builtin_amdgcn_mfma_f32_16x16x32_bf16(la[mi], lb[ni], z, 0, 0, 0);
  }
  asm volatile("s_waitcnt vmcnt(4)" ::: "memory");   // t0's 4 halves landed; t1's B pair in flight
  BAR();

  auto tile_step = [&](int t, auto bufc, auto sac, auto sbc, auto vmc) {
    constexpr int BUF = decltype(bufc)::value;
    constexpr int SA  = decltype(sac)::value;   // stage A0,A1(t+1) -> BUF^1 at ph1,ph2
    constexpr int SB  = decltype(sbc)::value;   // stage B0,B1(t+2) -> BUF at ph3,ph4
    constexpr int VM  = decltype(vmc)::value;   // ph4-end vmcnt: 4, 0, or -1

    // ---- ph1: read B-all(8) + A-sub q0(4); stage A0(t+1); MFMA q0
    #pragma unroll
    for (int ni = 0; ni < 4; ++ni) { bfr[ni][0] = RDB_(BUF, ni, 0); bfr[ni][1] = RDB_(BUF, ni, 1); }
    #pragma unroll
    for (int mi = 0; mi < 2; ++mi) { af[mi][0] = RDA_(BUF, 0, mi, 0); af[mi][1] = RDA_(BUF, 0, mi, 1); }
    if constexpr (SA) STAGE_A(BUF ^ 1, 0, t + 1);
    BAR();
    __builtin_amdgcn_s_setprio(1);
    #pragma unroll
    for (int mi = 0; mi < 2; ++mi)
      #pragma unroll
      for (int ni = 0; ni < 4; ++ni) {
        acc[mi][ni] = __builtin_amdgcn_mfma_f32_16x16x32_bf16(af[mi][0], bfr[ni][0], acc[mi][ni], 0, 0, 0);
        acc[mi][ni] = __builtin_amdgcn_mfma_f32_16x16x32_bf16(af[mi][1], bfr[ni][1], acc[mi][ni], 0, 0, 0);
      }
    __builtin_amdgcn_s_setprio(0);
    BAR();

    // ---- ph2: read A-sub q1; stage A1(t+1); MFMA q1
    #pragma unroll
    for (int mi = 0; mi < 2; ++mi) { af[mi][0] = RDA_(BUF, 1, mi, 0); af[mi][1] = RDA_(BUF, 1, mi, 1); }
    if constexpr (SA) STAGE_A(BUF ^ 1, 1, t + 1);
    BAR();
    __builtin_amdgcn_s_setprio(1);
    #pragma unroll
    for (int mi = 0; mi < 2; ++mi)
      #pragma unroll
      for (int ni = 0; ni < 4; ++ni) {
        acc[2+mi][ni] = __builtin_amdgcn_mfma_f32_16x16x32_bf16(af[mi][0], bfr[ni][0], acc[2+mi][ni], 0, 0, 0);
        acc[2+mi][ni] = __builtin_amdgcn_mfma_f32_16x16x32_bf16(af[mi][1], bfr[ni][1], acc[2+mi][ni], 0, 0, 0);
      }
    __builtin_amdgcn_s_setprio(0);
    BAR();

    // ---- ph3: read A-sub q2; stage B0(t+2) (B(buf) dead after ph1); MFMA q2
    #pragma unroll
    for (int mi = 0; mi < 2; ++mi) { af[mi][0] = RDA_(BUF, 2, mi, 0); af[mi][1] = RDA_(BUF, 2, mi, 1); }
    if constexpr (SB) STAGE_B(BUF, 0, t + 2);
    BAR();
    __builtin_amdgcn_s_setprio(1);
    #pragma unroll
    for (int mi = 0; mi < 2; ++mi)
      #pragma unroll
      for (int ni = 0; ni < 4; ++ni) {
        acc[4+mi][ni] = __builtin_amdgcn_mfma_f32_16x16x32_bf16(af[mi][0], bfr[ni][0], acc[4+mi][ni], 0, 0, 0);
        acc[4+mi][ni] = __builtin_amdgcn_mfma_f32_16x16x32_bf16(af[mi][1], bfr[ni][1], acc[4+mi][ni], 0, 0, 0);
      }
    __builtin_amdgcn_s_setprio(0);
    BAR();

    // ---- ph4: read A-sub q3; stage B1(t+2); MFMA q3; vmcnt at end
    #pragma unroll
    for (int mi = 0; mi < 2; ++mi) { af[mi][0] = RDA_(BUF, 3, mi, 0); af[mi][1] = RDA_(BUF, 3, mi, 1); }
    if constexpr (SB) STAGE_B(BUF, 1, t + 2);
    BAR();
    __builtin_amdgcn_s_setprio(1);
    #pragma unroll
    for (int mi = 0; mi < 2; ++mi)
      #pragma unroll
      for (int ni = 0; ni < 4; ++ni) {
        acc[6+mi][ni] = __builtin_amdgcn_mfma_f32_16x16x32_bf16(af[mi][0], bfr[ni][0], acc[6+mi][ni], 0, 0, 0);
        acc[6+mi][ni] = __builtin_amdgcn_mfma_f32_16x16x32_bf16(af[mi][1], bfr[ni][1], acc[6+mi][ni], 0, 0, 0);
      }
    __builtin_amdgcn_s_setprio(0);
    if constexpr (VM == 4)      asm volatile("s_waitcnt vmcnt(4)" ::: "memory");
    else if constexpr (VM == 0) asm volatile("s_waitcnt vmcnt(0)" ::: "memory");
    BAR();
  };

  for (int t = 0; t < NT - 2; t += 2) {
    tile_step(t,     IC<0>{}, IC<1>{}, IC<1>{}, IC<4>{});
    tile_step(t + 1, IC<1>{}, IC<1>{}, IC<1>{}, IC<4>{});
  }
  tile_step(NT - 2, IC<0>{}, IC<1>{}, IC<0>{}, IC<0>{});
  tile_step(NT - 1, IC<1>{}, IC<0>{}, IC<0>{}, IC<-1>{});

  // ---- epilogue: + bias, store f32 ----
  #pragma unroll
  for (int ni = 0; ni < 4; ++ni) {
    int col = n0 + ni * 16 + l15;
    float bv = bias[col];
    #pragma unroll
    for (int mi = 0; mi < 8; ++mi) {
      int r = m0 + mi * 16 + hi * 4;
      #pragma unroll
      for (int j = 0; j < 4; ++j)
        out[(size_t)(r + j) * N_TOT + col] = acc[mi][ni][j] + bv;
    }
  }
}

// ---------------- launcher ----------------
extern "C" void kernel_launch(void* const* d_in, const int* in_sizes, int n_in,
                              void* d_out, int out_size, void* d_ws, size_t ws_size,
                              hipStream_t stream) {
  const float* x    = (const float*)d_in[0];   // [8,2048,2048]
  const float* Ap   = (const float*)d_in[1];   // [8,2048,16]
  const float* Bp   = (const float*)d_in[2];   // [8,16,2048]
  const float* W    = (const float*)d_in[3];   // [2048,2048]
  const float* bias = (const float*)d_in[4];   // [2048]
  float* out = (float*)d_out;

  char* ws = (char*)d_ws;
  unsigned short* xbf     = (unsigned short*)(ws);                        // 64 MiB
  unsigned short* wbf     = (unsigned short*)(ws + 67108864);             // 8 MiB
  unsigned short* abf     = (unsigned short*)(ws + 67108864 + 8388608);   // 1 MiB
  unsigned short* interbf = (unsigned short*)(ws + 67108864 + 8388608 + 1048576); // 1 MiB

  k_prep<<<dim3(3136), dim3(256), 0, stream>>>(x, Bp, W, Ap, xbf, interbf, wbf, abf);
  k_gemm<<<dim3(512), dim3(512), 0, stream>>>(xbf, wbf, interbf, abf, bias, out);
}